// Round 2
// 571.126 us; speedup vs baseline: 1.0310x; 1.0310x over previous
//
#include <hip/hip_runtime.h>

// Problem constants
// x: (16, 64, 224, 224) f32, pw/pb: (64,16,16) f32, comp: (128,3,3) f32
// out: (16, 128, 222, 222) f32
// Identity: conv kernel is channel-broadcast =>
//   out[b,o,i,j] = sum_{kh,kw} comp[o,kh,kw] * s[b,i+kh,j+kw]
//   s[b,h,w]     = sum_c x[b,c,h,w]*pw[c,h%16,w%16]  +  pbsum[h%16,w%16]
//   pbsum[p,q]   = sum_c pb[c,p,q]      (x-independent -> hoisted prepass)

#define NB 16
#define NC 64
#define NH 224
#define NW 224
#define NO 128
#define OH 222
#define OW 222

#define S_BYTES ((size_t)NB * NH * NW * sizeof(float))   // 3,211,264 B

// float4-shaped but only 8-B-aligned (out rows are 888 B = 8-aligned only)
struct __attribute__((packed, aligned(8))) f4u { float x, y, z, w; };

// ---------------- Stage 0: bias channel-sum table (256 floats) ----------------
__global__ __launch_bounds__(256) void biassum_kernel(
    const float* __restrict__ pb, float* __restrict__ pbsum)
{
    int t = threadIdx.x;                       // hp*16 + wq
    float a = 0.f;
    #pragma unroll
    for (int c = 0; c < NC; ++c) a += pb[c * 256 + t];
    pbsum[t] = a;
}

// ---------------- Stage 1: channel reduction -> s (16,224,224) ----------------
// Thread owns float4 quads of TWO rows (h, h+112): same h%16 -> one pw load
// feeds two x loads. VMEM loads per s-quad: 1.5 (was 3).
// 100352 quad-pairs = 16*112*56 threads = 784 blocks * 128.
__global__ __launch_bounds__(128) void chansum2_kernel(
    const float* __restrict__ x, const float* __restrict__ pw,
    const float* __restrict__ pbsum, float* __restrict__ s)
{
    int q   = blockIdx.x * 128 + threadIdx.x;  // [0, 100352)
    int w4  = q % 56;
    int tmp = q / 56;
    int h   = tmp % 112;                       // row pair (h, h+112); (h+112)&15 == h&15
    int b   = tmp / 112;
    int w0  = w4 * 4;
    int hp  = h & 15;
    int wq  = w0 & 15;                         // 0,4,8,12 -> float4-aligned

    const float4* xp0 = (const float4*)(x + (((size_t)b * NC) * NH + h) * NW + w0);
    const float4* xp1 = xp0 + (112 * NW / 4);              // +112 rows
    const float4* pwp = (const float4*)(pw + hp * 16 + wq);

    float4 a0 = make_float4(0.f, 0.f, 0.f, 0.f);
    float4 a1 = make_float4(0.f, 0.f, 0.f, 0.f);
    #pragma unroll 8
    for (int c = 0; c < NC; ++c) {
        float4 x0 = xp0[(size_t)c * (NH * NW / 4)];        // stride 224*224 floats
        float4 x1 = xp1[(size_t)c * (NH * NW / 4)];
        float4 wv = pwp[c * 64];                           // stride 256 floats
        a0.x = fmaf(x0.x, wv.x, a0.x);
        a0.y = fmaf(x0.y, wv.y, a0.y);
        a0.z = fmaf(x0.z, wv.z, a0.z);
        a0.w = fmaf(x0.w, wv.w, a0.w);
        a1.x = fmaf(x1.x, wv.x, a1.x);
        a1.y = fmaf(x1.y, wv.y, a1.y);
        a1.z = fmaf(x1.z, wv.z, a1.z);
        a1.w = fmaf(x1.w, wv.w, a1.w);
    }
    float4 bv = *(const float4*)(pbsum + hp * 16 + wq);
    a0.x += bv.x; a0.y += bv.y; a0.z += bv.z; a0.w += bv.w;
    a1.x += bv.x; a1.y += bv.y; a1.z += bv.z; a1.w += bv.w;

    size_t so = ((size_t)b * NH + h) * NW + w0;
    *(float4*)(s + so)                    = a0;
    *(float4*)(s + so + (size_t)112 * NW) = a1;
}

// ---------------- Stage 2: 3x3 conv, 128 output channels ----------------
// Block = (b, row-pair). 128 threads = 2 waves, wave r owns row i = 2*ig + r.
// Lane jp (0..55) owns j quad [4jp, 4jp+3]; jp==55 owns the float2 tail (220,221).
// s values (18 floats) in registers across all 128 o; comp is wave-uniform
// (scalar loads); float4 stores = 896 B per wave-store.
__global__ __launch_bounds__(128) void conv2_kernel(
    const float* __restrict__ s, const float* __restrict__ comp,
    float* __restrict__ out)
{
    int bi = blockIdx.x;            // b*111 + ig
    int b  = bi / 111;
    int ig = bi - b * 111;
    int r  = threadIdx.x >> 6;      // 0..1
    int jp = threadIdx.x & 63;
    int i  = 2 * ig + r;            // 0..221
    if (jp >= 56) return;
    int j0 = jp * 4;                // 0..220

    float rv[3][6];
    #pragma unroll
    for (int kh = 0; kh < 3; ++kh) {
        const float* sp = s + (((size_t)b * NH) + i + kh) * NW + j0;
        float4 v = *(const float4*)sp;              // s rows are 896 B = 64-aligned
        rv[kh][0] = v.x; rv[kh][1] = v.y; rv[kh][2] = v.z; rv[kh][3] = v.w;
        if (jp < 55) {
            float2 t = *(const float2*)(sp + 4);
            rv[kh][4] = t.x; rv[kh][5] = t.y;
        } else {                                    // j=224,225 don't exist; unused
            rv[kh][4] = 0.f; rv[kh][5] = 0.f;
        }
    }

    float* outp = out + ((size_t)b * NO * OH + i) * OW + j0;
    const size_t ostride = (size_t)OH * OW;         // 49284 floats per o

    #pragma unroll 4
    for (int o = 0; o < NO; ++o) {
        const float* cw = comp + o * 9;             // wave-uniform -> s_load
        float a0 = 0.f, a1 = 0.f, a2 = 0.f, a3 = 0.f;
        #pragma unroll
        for (int kh = 0; kh < 3; ++kh) {
            float c0 = cw[kh * 3 + 0], c1 = cw[kh * 3 + 1], c2 = cw[kh * 3 + 2];
            a0 = fmaf(rv[kh][0], c0, a0);
            a0 = fmaf(rv[kh][1], c1, a0);
            a0 = fmaf(rv[kh][2], c2, a0);
            a1 = fmaf(rv[kh][1], c0, a1);
            a1 = fmaf(rv[kh][2], c1, a1);
            a1 = fmaf(rv[kh][3], c2, a1);
            a2 = fmaf(rv[kh][2], c0, a2);
            a2 = fmaf(rv[kh][3], c1, a2);
            a2 = fmaf(rv[kh][4], c2, a2);
            a3 = fmaf(rv[kh][3], c0, a3);
            a3 = fmaf(rv[kh][4], c1, a3);
            a3 = fmaf(rv[kh][5], c2, a3);
        }
        float* op = outp + (size_t)o * ostride;
        if (jp < 55) {
            f4u v; v.x = a0; v.y = a1; v.z = a2; v.w = a3;
            *(f4u*)op = v;                          // dwordx4, 8-B aligned ok
        } else {
            *(float2*)op = make_float2(a0, a1);     // tail j=220,221
        }
    }
}

// ---------------- Fallback: fused single kernel (no workspace) ----------------
__global__ __launch_bounds__(128) void fused_kernel(
    const float* __restrict__ x, const float* __restrict__ pw,
    const float* __restrict__ pb, const float* __restrict__ comp,
    float* __restrict__ out)
{
    __shared__ float s[3 * NW];
    int bi = blockIdx.x;
    int b  = bi / OH;
    int i  = bi - b * OH;

    for (int p = threadIdx.x; p < 3 * NW; p += 128) {
        int rr = p / NW, w = p - rr * NW;
        int h  = i + rr;
        int hp = h & 15, wq = w & 15;
        const float* xp  = x + (((size_t)b * NC) * NH + h) * NW + w;
        const float* pwp = pw + hp * 16 + wq;
        const float* pbp = pb + hp * 16 + wq;
        float acc = 0.f;
        for (int c = 0; c < NC; ++c)
            acc = fmaf(xp[(size_t)c * NH * NW], pwp[c * 256], acc) + pbp[c * 256];
        s[p] = acc;
    }
    __syncthreads();

    int jp = threadIdx.x;
    if (jp >= OW / 2) return;

    float rr[3][4];
    #pragma unroll
    for (int kh = 0; kh < 3; ++kh)
        #pragma unroll
        for (int m = 0; m < 4; ++m)
            rr[kh][m] = s[kh * NW + 2 * jp + m];

    float2* outp = (float2*)out + ((size_t)b * NO * OH + i) * (OW / 2) + jp;
    const size_t ostride = (size_t)OH * (OW / 2);

    #pragma unroll 4
    for (int o = 0; o < NO; ++o) {
        const float* cw = comp + o * 9;
        float a0 = 0.f, a1 = 0.f;
        #pragma unroll
        for (int kh = 0; kh < 3; ++kh) {
            float c0 = cw[kh * 3 + 0], c1 = cw[kh * 3 + 1], c2 = cw[kh * 3 + 2];
            a0 = fmaf(rr[kh][0], c0, a0);
            a0 = fmaf(rr[kh][1], c1, a0);
            a0 = fmaf(rr[kh][2], c2, a0);
            a1 = fmaf(rr[kh][1], c0, a1);
            a1 = fmaf(rr[kh][2], c1, a1);
            a1 = fmaf(rr[kh][3], c2, a1);
        }
        outp[(size_t)o * ostride] = make_float2(a0, a1);
    }
}

extern "C" void kernel_launch(void* const* d_in, const int* in_sizes, int n_in,
                              void* d_out, int out_size, void* d_ws, size_t ws_size,
                              hipStream_t stream) {
    const float* x    = (const float*)d_in[0];
    const float* pw   = (const float*)d_in[1];
    const float* pb   = (const float*)d_in[2];
    const float* comp = (const float*)d_in[3];
    float* out = (float*)d_out;

    if (ws_size >= S_BYTES + 1024) {
        float* s     = (float*)d_ws;
        float* pbsum = (float*)((char*)d_ws + S_BYTES);
        biassum_kernel<<<1, 256, 0, stream>>>(pb, pbsum);
        chansum2_kernel<<<784, 128, 0, stream>>>(x, pw, pbsum, s);
        conv2_kernel<<<NB * 111, 128, 0, stream>>>(s, comp, out);
    } else {
        fused_kernel<<<NB * OH, 128, 0, stream>>>(x, pw, pb, comp, out);
    }
}

// Round 3
// 561.418 us; speedup vs baseline: 1.0489x; 1.0173x over previous
//
#include <hip/hip_runtime.h>

// x: (16, 64, 224, 224) f32, pw/pb: (64,16,16) f32, comp: (128,3,3) f32
// out: (16, 128, 222, 222) f32
// Identity: conv kernel is channel-broadcast =>
//   out[b,o,i,j] = sum_{kh,kw} comp[o,kh,kw] * s[b,i+kh,j+kw]
//   s[b,h,w]     = sum_c x[b,c,h,w]*pw[c,h%16,w%16]  +  pbsum[h%16,w%16]
//   pbsum[p,q]   = sum_c pb[c,p,q]      (x-independent -> hoisted prepass)
//
// Fully fused: block = (b, 6-output-row tile). Stage A computes the 8-row
// s-tile into LDS (waves 0..6 read a CONTIGUOUS 7168-B window per channel
// plane). Stage B: each wave owns 16 o-planes and writes 6 contiguous rows
// (5328 B) per plane visit -> DRAM-friendly write streams.

#define NB 16
#define NC 64
#define NH 224
#define NW 224
#define NO 128
#define OH 222
#define OW 222
#define TI 6                 // output rows per block
#define NT 37                // 37 * 6 = 222
#define SROWS (TI + 2)       // 8 s-rows per block

// float4-shaped but only 8-B-aligned (out rows are 888 B = 8-aligned only)
struct __attribute__((packed, aligned(8))) f4u { float x, y, z, w; };

// ---------------- Stage 0: bias channel-sum table (256 floats) ----------------
__global__ __launch_bounds__(256) void biassum_kernel(
    const float* __restrict__ pb, float* __restrict__ pbsum)
{
    int t = threadIdx.x;                       // hp*16 + wq
    float a = 0.f;
    #pragma unroll
    for (int c = 0; c < NC; ++c) a += pb[c * 256 + t];
    pbsum[t] = a;
}

// ---------------- Fused main kernel ----------------
// 512 threads = 8 waves. Stage A: 448 tasks (8 rows x 56 quads) = waves 0..6,
// each wave reads 1024 B contiguous per channel plane; the block covers a
// contiguous 7168-B window of each plane. Stage B: wave w owns o in
// {w, w+8, ..., w+120}; per o it computes+stores all 6 rows (contiguous
// 5328 B region of that o-plane).
template<bool USE_PBSUM>
__global__ __launch_bounds__(512) void fused6_kernel(
    const float* __restrict__ x, const float* __restrict__ pw,
    const float* __restrict__ pbx,        // pbsum (256 f) or raw pb (64x256 f)
    const float* __restrict__ comp, float* __restrict__ out)
{
    __shared__ __align__(16) float s[SROWS * NW];   // 7168 B

    int blk = blockIdx.x;
    int b   = blk / NT;
    int it  = blk - b * NT;
    int i0  = it * TI;                   // 0..216
    int tid = threadIdx.x;

    // ---- Stage A: channel reduction into LDS s[8][224] ----
    if (tid < SROWS * (NW / 4)) {        // 448 tasks, waves 0..6 fully active
        int row = tid / (NW / 4);        // 0..7
        int w4  = tid - row * (NW / 4);  // 0..55
        int h   = i0 + row;              // <= 223
        int w0  = 4 * w4;
        int hp  = h & 15;
        int wq  = w0 & 15;               // 0,4,8,12 -> float4-aligned

        const float4* xp  = (const float4*)(x + (((size_t)b * NC) * NH + h) * NW + w0);
        const float4* pwp = (const float4*)(pw + hp * 16 + wq);

        float4 a = make_float4(0.f, 0.f, 0.f, 0.f);
        if (USE_PBSUM) {
            #pragma unroll 8
            for (int c = 0; c < NC; ++c) {
                float4 xv = xp[(size_t)c * (NH * NW / 4)];   // stride 224*224 floats
                float4 wv = pwp[c * 64];                     // stride 256 floats
                a.x = fmaf(xv.x, wv.x, a.x);
                a.y = fmaf(xv.y, wv.y, a.y);
                a.z = fmaf(xv.z, wv.z, a.z);
                a.w = fmaf(xv.w, wv.w, a.w);
            }
            float4 bv = *(const float4*)(pbx + hp * 16 + wq);
            a.x += bv.x; a.y += bv.y; a.z += bv.z; a.w += bv.w;
        } else {
            const float4* pbp = (const float4*)(pbx + hp * 16 + wq);
            #pragma unroll 8
            for (int c = 0; c < NC; ++c) {
                float4 xv = xp[(size_t)c * (NH * NW / 4)];
                float4 wv = pwp[c * 64];
                float4 bv = pbp[c * 64];
                a.x = fmaf(xv.x, wv.x, a.x) + bv.x;
                a.y = fmaf(xv.y, wv.y, a.y) + bv.y;
                a.z = fmaf(xv.z, wv.z, a.z) + bv.z;
                a.w = fmaf(xv.w, wv.w, a.w) + bv.w;
            }
        }
        *(float4*)(&s[row * NW + w0]) = a;
    }
    __syncthreads();

    // ---- Stage B: 3x3 conv over 128 o, 6 rows per block ----
    int wave = tid >> 6;
    int jp   = tid & 63;
    if (jp >= 56) return;                // after the barrier: safe
    int j0 = 4 * jp;                     // 0..220

    // 8 s-rows x 6 cols in registers (48 VGPR)
    float rv[SROWS][6];
    #pragma unroll
    for (int r = 0; r < SROWS; ++r) {
        const float* sp = &s[r * NW + j0];
        float4 v = *(const float4*)sp;   // 16-B aligned (16*jp)
        rv[r][0] = v.x; rv[r][1] = v.y; rv[r][2] = v.z; rv[r][3] = v.w;
        if (jp < 55) {
            float2 t = *(const float2*)(sp + 4);
            rv[r][4] = t.x; rv[r][5] = t.y;
        } else {
            rv[r][4] = 0.f; rv[r][5] = 0.f;   // j=224,225 don't exist; unused
        }
    }

    #pragma unroll 2
    for (int oi = 0; oi < NO / 8; ++oi) {
        int o = wave + 8 * oi;                       // wave-uniform
        const float* cw = comp + o * 9;              // -> s_load
        float c00 = cw[0], c01 = cw[1], c02 = cw[2];
        float c10 = cw[3], c11 = cw[4], c12 = cw[5];
        float c20 = cw[6], c21 = cw[7], c22 = cw[8];

        float* obase = out + (((size_t)b * NO + o) * OH + i0) * OW + j0;
        #pragma unroll
        for (int row = 0; row < TI; ++row) {
            const float* r0 = rv[row + 0];
            const float* r1 = rv[row + 1];
            const float* r2 = rv[row + 2];
            float a0 = 0.f, a1 = 0.f, a2 = 0.f, a3 = 0.f;
            a0 = fmaf(r0[0], c00, a0); a0 = fmaf(r0[1], c01, a0); a0 = fmaf(r0[2], c02, a0);
            a0 = fmaf(r1[0], c10, a0); a0 = fmaf(r1[1], c11, a0); a0 = fmaf(r1[2], c12, a0);
            a0 = fmaf(r2[0], c20, a0); a0 = fmaf(r2[1], c21, a0); a0 = fmaf(r2[2], c22, a0);
            a1 = fmaf(r0[1], c00, a1); a1 = fmaf(r0[2], c01, a1); a1 = fmaf(r0[3], c02, a1);
            a1 = fmaf(r1[1], c10, a1); a1 = fmaf(r1[2], c11, a1); a1 = fmaf(r1[3], c12, a1);
            a1 = fmaf(r2[1], c20, a1); a1 = fmaf(r2[2], c21, a1); a1 = fmaf(r2[3], c22, a1);
            a2 = fmaf(r0[2], c00, a2); a2 = fmaf(r0[3], c01, a2); a2 = fmaf(r0[4], c02, a2);
            a2 = fmaf(r1[2], c10, a2); a2 = fmaf(r1[3], c11, a2); a2 = fmaf(r1[4], c12, a2);
            a2 = fmaf(r2[2], c20, a2); a2 = fmaf(r2[3], c21, a2); a2 = fmaf(r2[4], c22, a2);
            a3 = fmaf(r0[3], c00, a3); a3 = fmaf(r0[4], c01, a3); a3 = fmaf(r0[5], c02, a3);
            a3 = fmaf(r1[3], c10, a3); a3 = fmaf(r1[4], c11, a3); a3 = fmaf(r1[5], c12, a3);
            a3 = fmaf(r2[3], c20, a3); a3 = fmaf(r2[4], c21, a3); a3 = fmaf(r2[5], c22, a3);

            float* op = obase + (size_t)row * OW;
            if (jp < 55) {
                f4u v; v.x = a0; v.y = a1; v.z = a2; v.w = a3;
                *(f4u*)op = v;                       // dwordx4, 8-B aligned ok
            } else {
                *(float2*)op = make_float2(a0, a1);  // tail j=220,221
            }
        }
    }
}

extern "C" void kernel_launch(void* const* d_in, const int* in_sizes, int n_in,
                              void* d_out, int out_size, void* d_ws, size_t ws_size,
                              hipStream_t stream) {
    const float* x    = (const float*)d_in[0];
    const float* pw   = (const float*)d_in[1];
    const float* pb   = (const float*)d_in[2];
    const float* comp = (const float*)d_in[3];
    float* out = (float*)d_out;

    if (ws_size >= 1024) {
        float* pbsum = (float*)d_ws;
        biassum_kernel<<<1, 256, 0, stream>>>(pb, pbsum);
        fused6_kernel<true><<<NB * NT, 512, 0, stream>>>(x, pw, pbsum, comp, out);
    } else {
        fused6_kernel<false><<<NB * NT, 512, 0, stream>>>(x, pw, pb, comp, out);
    }
}